// Round 4
// baseline (680.209 us; speedup 1.0000x reference)
//
#include <hip/hip_runtime.h>
#include <hip/hip_bf16.h>

constexpr int NN    = 30000;   // total nodes
constexpr int NCELL = 66;
constexpr int NF    = 256;     // features
constexpr int CAP   = 80;      // bucket capacity per col (in-deg mean 32, P(>80)~1e-8)
constexpr float EPS = 1e-5f;

using bf16x8 = __attribute__((ext_vector_type(8))) short;   // 8 bf16 = 4 VGPRs
using f32x4  = __attribute__((ext_vector_type(4))) float;

__device__ __forceinline__ float bf2f(unsigned short u) {
    return __uint_as_float(((unsigned)u) << 16);
}
__device__ __forceinline__ unsigned short f2bf(float f) {
    __hip_bfloat16 h = __float2bfloat16(f);   // RNE
    return *reinterpret_cast<unsigned short*>(&h);
}
// accumulate 8 bf16 features packed in a float4 (bit halves), f32 math
__device__ __forceinline__ void acc8(float* acc, float4 u, float w) {
    unsigned a = __float_as_uint(u.x), b = __float_as_uint(u.y);
    unsigned c = __float_as_uint(u.z), d = __float_as_uint(u.w);
    acc[0] += w * __uint_as_float(a << 16);
    acc[1] += w * __uint_as_float(a & 0xffff0000u);
    acc[2] += w * __uint_as_float(b << 16);
    acc[3] += w * __uint_as_float(b & 0xffff0000u);
    acc[4] += w * __uint_as_float(c << 16);
    acc[5] += w * __uint_as_float(c & 0xffff0000u);
    acc[6] += w * __uint_as_float(d << 16);
    acc[7] += w * __uint_as_float(d & 0xffff0000u);
}

// ---------------- init: fill/sums = 0 ----------------
__global__ void k_init(int* fill, float* sums) {
    int i = blockIdx.x * 256 + threadIdx.x;
    if (i < NN) fill[i] = 0;
    if (i < 2 * NF) sums[i] = 0.0f;
}

__global__ void k_zero_stats(float* sums) {
    int i = threadIdx.x;
    if (i < 2 * NF) sums[i] = 0.0f;
}

// ---------------- convert W (f32, o-major k-contig) -> bf16 ----------------
__global__ void k_cvtw(const float4* __restrict__ W, ushort4* __restrict__ Wh) {
    int idx = blockIdx.x * 256 + threadIdx.x;
    if (idx >= NF * NF / 4) return;
    float4 v = W[idx];
    ushort4 o;
    o.x = f2bf(v.x); o.y = f2bf(v.y); o.z = f2bf(v.z); o.w = f2bf(v.w);
    Wh[idx] = o;
}

// ------- scatter edges into fixed-capacity buckets: 1 atomic + one 4B nt store -----
// (round-0 form: nt store measured 77us vs cached 85us; L2 can't coalesce these)
__global__ void k_scatter(const int* __restrict__ ei, const float* __restrict__ ew,
                          int* fill, unsigned* __restrict__ bkt, int E) {
    int e = blockIdx.x * 256 + threadIdx.x;
    if (e >= E) return;
    int row = ei[e];
    int col = ei[E + e];
    unsigned q = (unsigned)(ew[e] * 65536.0f);        // trunc; ew<1 => q<=65535
    int pos = atomicAdd(&fill[col], 1);
    unsigned v = ((unsigned)row) | (q << 16);
    __builtin_nontemporal_store(v, &bkt[(size_t)col * CAP + pos]);
}

// ------- per-col degree from bucket (exact int sum of ewq), emit scales -----------
// s1 = dinv^2 (hops 1-2 row scale = D^-1), s2 = dinv (hop-3 scale & input pre-scale)
__global__ void k_deg(const unsigned* __restrict__ bkt, const int* __restrict__ fill,
                      float* __restrict__ s1, float* __restrict__ s2) {
    int i = blockIdx.x * 256 + threadIdx.x;
    if (i >= NN) return;
    int cnt = fill[i];
    unsigned sq = 0;
    const unsigned* p = bkt + (size_t)i * CAP;
    for (int e = 0; e < cnt; e++) sq += (p[e] >> 16);
    float deg = 1.0f + (float)sq * (1.0f / 65536.0f);
    float di = rsqrtf(deg);
    s2[i] = di;
    s1[i] = di * di;
}

// ---------------- concat (cell ++ sub), pre-scale by dinv, f32 -> bf16 ------------
__global__ void k_concat_h(const float4* __restrict__ cell, const float4* __restrict__ sub,
                           const float* __restrict__ dinv, ushort4* __restrict__ xh) {
    int idx = blockIdx.x * 256 + threadIdx.x;          // float4 index
    if (idx >= NN * (NF / 4)) return;
    const int CELL4 = NCELL * (NF / 4);
    float4 v = (idx < CELL4) ? cell[idx] : sub[idx - CELL4];
    float di = dinv[idx >> 6];
    ushort4 o;
    o.x = f2bf(v.x * di); o.y = f2bf(v.y * di);
    o.z = f2bf(v.z * di); o.w = f2bf(v.w * di);
    xh[idx] = o;
}

// ------------- one hop: t = (A+I) x, then row-scale; bf16 in/out, f32 accum --------
// Chunk-phased for L2 residency WITHOUT XCD-mapping bets: feature dim split in 4
// chunks of 64 feats (128B); chunk is the OUTERMOST block dim (c = bid/7500).
// Blocks dispatch ~in ascending order, so co-resident blocks share one chunk ->
// every XCD's gather working set is 30000 x 128B = 3.75MB <= 4MB L2 -> L2 hits.
// Degrades gracefully (to today's L3 path) if dispatch order is unfriendly.
// Wave = (node, chunk): lanes = 8 edge-groups x 8 float4-slots; bounds-predicated
// 4-deep unroll = 32 edges in flight. Meta nt-loads (don't evict hot chunk);
// output nt-stores from 8 adjacent lanes (full 64B lines, no amplification).
__global__ __launch_bounds__(256) void k_prop(const ushort* __restrict__ xin,
                                              ushort* __restrict__ xout,
                                              const int* __restrict__ fill,
                                              const unsigned* __restrict__ bkt,
                                              const float* __restrict__ scale) {
    constexpr int NB = NN / 4;           // 7500 blocks per chunk
    int c    = blockIdx.x / NB;          // feature chunk 0..3 (64 feats = 8 float4)
    int idx  = blockIdx.x - c * NB;
    int n    = idx * 4 + (threadIdx.x >> 6);
    int lane = threadIdx.x & 63;
    int eg   = lane >> 3;                // edge group 0..7
    int f    = lane & 7;                 // float4 slot within 128B chunk
    const float4* xl = (const float4*)xin + c * 8 + f;   // + r*32 per row
    const unsigned* base = bkt + (size_t)n * CAP;
    int cnt = fill[n];
    float acc[8];
    #pragma unroll
    for (int i = 0; i < 8; i++) acc[i] = 0.f;
    for (int e0 = 0; e0 < cnt; e0 += 32) {               // 32 edges (4-deep) in flight
        int e = e0 + eg;
        unsigned m0 = (e < cnt)      ? __builtin_nontemporal_load(base + e)      : 0u;
        unsigned m1 = (e + 8 < cnt)  ? __builtin_nontemporal_load(base + e + 8)  : 0u;
        unsigned m2 = (e + 16 < cnt) ? __builtin_nontemporal_load(base + e + 16) : 0u;
        unsigned m3 = (e + 24 < cnt) ? __builtin_nontemporal_load(base + e + 24) : 0u;
        int r0 = (int)(m0 & 0xffffu), r1 = (int)(m1 & 0xffffu);
        int r2 = (int)(m2 & 0xffffu), r3 = (int)(m3 & 0xffffu);
        float w0 = (float)(m0 >> 16) * (1.0f / 65536.0f);
        float w1 = (float)(m1 >> 16) * (1.0f / 65536.0f);
        float w2 = (float)(m2 >> 16) * (1.0f / 65536.0f);
        float w3 = (float)(m3 >> 16) * (1.0f / 65536.0f);
        float4 u0 = xl[r0 * 32];
        float4 u1 = xl[r1 * 32];
        float4 u2 = xl[r2 * 32];
        float4 u3 = xl[r3 * 32];
        acc8(acc, u0, w0); acc8(acc, u1, w1);
        acc8(acc, u2, w2); acc8(acc, u3, w3);
    }
    // reduce across the 8 edge groups (lane bits 3..5)
    #pragma unroll
    for (int i = 0; i < 8; i++) {
        acc[i] += __shfl_xor(acc[i], 8);
        acc[i] += __shfl_xor(acc[i], 16);
        acc[i] += __shfl_xor(acc[i], 32);
    }
    if (eg == 0) {
        float4 u = xl[n * 32];
        acc8(acc, u, 1.0f);                // self loop, raw weight 1
        float sc = scale[n];
        #pragma unroll
        for (int i = 0; i < 8; i++) acc[i] *= sc;
        unsigned p0 = ((unsigned)f2bf(acc[1]) << 16) | f2bf(acc[0]);
        unsigned p1 = ((unsigned)f2bf(acc[3]) << 16) | f2bf(acc[2]);
        unsigned p2 = ((unsigned)f2bf(acc[5]) << 16) | f2bf(acc[4]);
        unsigned p3 = ((unsigned)f2bf(acc[7]) << 16) | f2bf(acc[6]);
        f32x4 o;
        o[0] = __uint_as_float(p0); o[1] = __uint_as_float(p1);
        o[2] = __uint_as_float(p2); o[3] = __uint_as_float(p3);
        __builtin_nontemporal_store(o, (f32x4*)xout + n * 32 + c * 8 + f);
    }
}

// ------- y[m][o] = PReLU(bias[o] + sum_k A[m][k] W[o][k]) -> f32, + BN stats ------
// r9-verified: wave = 16 rows x full 256 cols (acc[16]); stats via LDS block-reduce
// (4 waves) -> 512 atomics/block. Invalid pad wave guarded (no early return).
__global__ __launch_bounds__(256) void k_gemm_fused(const short* __restrict__ A,  // NN x 256 bf16
                                                    const short* __restrict__ B,  // 256 x 256 bf16 (W)
                                                    const float* __restrict__ bias,
                                                    const float* __restrict__ pw,
                                                    float* __restrict__ y,        // NN x 256 f32
                                                    float* __restrict__ sums) {
    constexpr int RT = NN / 16;        // 1875 row tiles
    int w    = threadIdx.x >> 6;       // wave in block
    int lane = threadIdx.x & 63;
    int rt   = blockIdx.x * 4 + w;     // 4 row tiles per block
    int ml   = lane & 15;              // row in tile (A) / col in 16-tile (B, D)
    int q    = lane >> 4;              // quad: A/B k = q*8+j, D row = q*4+r
    bool valid = rt < RT;
    __shared__ float red[2][4][NF];    // [s|s2][wave][col] = 8 KB
    f32x4 acc[16];
    #pragma unroll
    for (int i = 0; i < 16; i++) acc[i] = (f32x4){0.f, 0.f, 0.f, 0.f};
    if (valid) {
        const short* arow = A + (rt * 16 + ml) * NF + q * 8;
        #pragma unroll
        for (int ks = 0; ks < 8; ks++) {
            bf16x8 a = *(const bf16x8*)(arow + ks * 32);
            #pragma unroll
            for (int nt = 0; nt < 16; nt++) {
                bf16x8 b = *(const bf16x8*)(B + (nt * 16 + ml) * NF + ks * 32 + q * 8);
                acc[nt] = __builtin_amdgcn_mfma_f32_16x16x32_bf16(a, b, acc[nt], 0, 0, 0);
            }
        }
    }
    #pragma unroll
    for (int nt = 0; nt < 16; nt++) {
        int col = nt * 16 + ml;
        float s = 0.f, s2 = 0.f;
        if (valid) {
            float bb = bias[col];
            float pc = pw[col];
            #pragma unroll
            for (int r = 0; r < 4; r++) {
                float v = acc[nt][r] + bb;
                v = (v >= 0.f) ? v : pc * v;
                s += v; s2 += v * v;
                y[(rt * 16 + q * 4 + r) * NF + col] = v;
            }
        }
        s  += __shfl_xor(s, 16);  s  += __shfl_xor(s, 32);
        s2 += __shfl_xor(s2, 16); s2 += __shfl_xor(s2, 32);
        if (lane < 16) { red[0][w][col] = s; red[1][w][col] = s2; }
    }
    __syncthreads();
    int t = threadIdx.x;               // t = col, all 256 threads
    float v0 = red[0][0][t] + red[0][1][t] + red[0][2][t] + red[0][3][t];
    float v1 = red[1][0][t] + red[1][1][t] + red[1][2][t] + red[1][3][t];
    atomicAdd(&sums[t], v0);
    atomicAdd(&sums[NF + t], v1);
}

// ---------------- finalize BN scale/shift ----------------
__global__ void k_finalize(const float* __restrict__ sums, const float* __restrict__ gamma,
                           const float* __restrict__ beta, float* __restrict__ ss) {
    int t = threadIdx.x;
    float mean = sums[t] / (float)NN;
    float var = sums[NF + t] / (float)NN - mean * mean;
    if (var < 0.f) var = 0.f;
    float istd = rsqrtf(var + EPS);
    float sc = gamma[t] * istd;
    ss[t] = sc;
    ss[NF + t] = beta[t] - mean * sc;
}

// -------- apply BN + dinv pre-scale: f32 y -> bf16 x (feeds next hop chain) -------
__global__ void k_apply_h(const float4* __restrict__ y, const float* __restrict__ ss,
                          const float* __restrict__ dinv, ushort4* __restrict__ xh) {
    int idx = blockIdx.x * 256 + threadIdx.x;          // float4 index
    if (idx >= NN * (NF / 4)) return;
    int f = (idx & 63) * 4;
    float di = dinv[idx >> 6];
    float4 v = y[idx];
    ushort4 o;
    o.x = f2bf((v.x * ss[f]     + ss[NF + f])     * di);
    o.y = f2bf((v.y * ss[f + 1] + ss[NF + f + 1]) * di);
    o.z = f2bf((v.z * ss[f + 2] + ss[NF + f + 2]) * di);
    o.w = f2bf((v.w * ss[f + 3] + ss[NF + f + 3]) * di);
    xh[idx] = o;
}

// ---------------- apply BN: f32 y -> f32 output ----------------
__global__ void k_apply_out(const float4* __restrict__ y, const float* __restrict__ ss,
                            float4* __restrict__ out) {
    int idx = blockIdx.x * 256 + threadIdx.x;          // float4 index
    if (idx >= NN * (NF / 4)) return;
    int f = (idx & 63) * 4;
    float4 v = y[idx];
    float4 o;
    o.x = v.x * ss[f]     + ss[NF + f];
    o.y = v.y * ss[f + 1] + ss[NF + f + 1];
    o.z = v.z * ss[f + 2] + ss[NF + f + 2];
    o.w = v.w * ss[f + 3] + ss[NF + f + 3];
    out[idx] = o;
}

extern "C" void kernel_launch(void* const* d_in, const int* in_sizes, int n_in,
                              void* d_out, int out_size, void* d_ws, size_t ws_size,
                              hipStream_t stream) {
    const float* cell  = (const float*)d_in[0];
    const float* sub   = (const float*)d_in[1];
    const int*   ei    = (const int*)  d_in[2];
    const float* ew    = (const float*)d_in[3];
    const float* W1    = (const float*)d_in[4];
    const float* bias1 = (const float*)d_in[5];
    const float* W2    = (const float*)d_in[6];
    const float* bias2 = (const float*)d_in[7];
    const float* pw    = (const float*)d_in[8];
    const float* gamma = (const float*)d_in[9];
    const float* beta  = (const float*)d_in[10];
    float* out = (float*)d_out;        // reference output dtype is float32
    const int E = in_sizes[3];         // 960000 directed edges

    char* ws = (char*)d_ws;
    size_t off = 0;
    auto alloc = [&](size_t bytes) -> void* {
        void* p = ws + off;
        off = (off + bytes + 255) & ~((size_t)255);
        return p;
    };
    ushort*   xh0  = (ushort*)  alloc((size_t)NN * NF * 2);     // bf16 x ping
    ushort*   xh1  = (ushort*)  alloc((size_t)NN * NF * 2);     // bf16 x pong
    float*    yf   = (float*)   alloc((size_t)NN * NF * 4);     // f32 prelu'd gemm out
    ushort*   W1h  = (ushort*)  alloc((size_t)NF * NF * 2);
    ushort*   W2h  = (ushort*)  alloc((size_t)NF * NF * 2);
    unsigned* bkt  = (unsigned*)alloc((size_t)NN * CAP * 4);    // 9.6 MB edge buckets
    int*      fill = (int*)     alloc((size_t)NN * 4);
    float*    s1   = (float*)   alloc((size_t)NN * 4);          // dinv^2
    float*    s2   = (float*)   alloc((size_t)NN * 4);          // dinv
    float*    sums = (float*)   alloc((size_t)2 * NF * 4);
    float*    ss   = (float*)   alloc((size_t)2 * NF * 4);

    const int gN  = (NN + 255) / 256;             // 118
    const int gE  = (E + 255) / 256;
    const int gV4 = (NN * NF / 4 + 255) / 256;    // 7500
    const int gW4 = (NF * NF / 4 + 255) / 256;    // 64
    const int gP  = NN;                           // 4 chunks x 7500 blocks (chunk outermost)
    const int gG  = (NN / 16 + 3) / 4;            // 469 blocks x 4 waves

    k_init<<<gN, 256, 0, stream>>>(fill, sums);
    k_cvtw<<<gW4, 256, 0, stream>>>((const float4*)W1, (ushort4*)W1h);
    k_cvtw<<<gW4, 256, 0, stream>>>((const float4*)W2, (ushort4*)W2h);
    k_scatter<<<gE, 256, 0, stream>>>(ei, ew, fill, bkt, E);
    k_deg<<<gN, 256, 0, stream>>>(bkt, fill, s1, s2);
    k_concat_h<<<gV4, 256, 0, stream>>>((const float4*)cell, (const float4*)sub, s2, (ushort4*)xh0);

    // ---------------- layer 1 ----------------
    k_prop<<<gP, 256, 0, stream>>>(xh0, xh1, fill, bkt, s1);
    k_prop<<<gP, 256, 0, stream>>>(xh1, xh0, fill, bkt, s1);
    k_prop<<<gP, 256, 0, stream>>>(xh0, xh1, fill, bkt, s2);
    k_gemm_fused<<<gG, 256, 0, stream>>>((const short*)xh1, (const short*)W1h, bias1, pw, yf, sums);
    k_finalize<<<1, 256, 0, stream>>>(sums, gamma, beta, ss);
    k_apply_h<<<gV4, 256, 0, stream>>>((const float4*)yf, ss, s2, (ushort4*)xh0);
    k_zero_stats<<<1, 512, 0, stream>>>(sums);

    // ---------------- layer 2 ----------------
    k_prop<<<gP, 256, 0, stream>>>(xh0, xh1, fill, bkt, s1);
    k_prop<<<gP, 256, 0, stream>>>(xh1, xh0, fill, bkt, s1);
    k_prop<<<gP, 256, 0, stream>>>(xh0, xh1, fill, bkt, s2);
    k_gemm_fused<<<gG, 256, 0, stream>>>((const short*)xh1, (const short*)W2h, bias2, pw, yf, sums);
    k_finalize<<<1, 256, 0, stream>>>(sums, gamma, beta, ss);
    k_apply_out<<<gV4, 256, 0, stream>>>((const float4*)yf, ss, (float4*)out);
}

// Round 5
// 654.038 us; speedup vs baseline: 1.0400x; 1.0400x over previous
//
#include <hip/hip_runtime.h>
#include <hip/hip_bf16.h>

constexpr int NN    = 30000;   // total nodes
constexpr int NCELL = 66;
constexpr int NF    = 256;     // features
constexpr int CAP   = 80;      // bucket capacity per col (in-deg mean 32, P(>80)~1e-8)
constexpr float EPS = 1e-5f;

using bf16x8 = __attribute__((ext_vector_type(8))) short;   // 8 bf16 = 4 VGPRs
using f32x4  = __attribute__((ext_vector_type(4))) float;
using f32x2  = __attribute__((ext_vector_type(2))) float;

__device__ __forceinline__ float bf2f(unsigned short u) {
    return __uint_as_float(((unsigned)u) << 16);
}
__device__ __forceinline__ unsigned short f2bf(float f) {
    __hip_bfloat16 h = __float2bfloat16(f);   // RNE
    return *reinterpret_cast<unsigned short*>(&h);
}
// accumulate 8 bf16 features packed in a float4 (bit halves) into 4x f32x2;
// packed-pair layout encourages v_pk_fma_f32 (halves VALU fma count)
__device__ __forceinline__ void acc8v(f32x2* acc, float4 u, float w) {
    unsigned a = __float_as_uint(u.x), b = __float_as_uint(u.y);
    unsigned c = __float_as_uint(u.z), d = __float_as_uint(u.w);
    f32x2 wv; wv[0] = w; wv[1] = w;
    f32x2 e0; e0[0] = __uint_as_float(a << 16); e0[1] = __uint_as_float(a & 0xffff0000u);
    f32x2 e1; e1[0] = __uint_as_float(b << 16); e1[1] = __uint_as_float(b & 0xffff0000u);
    f32x2 e2; e2[0] = __uint_as_float(c << 16); e2[1] = __uint_as_float(c & 0xffff0000u);
    f32x2 e3; e3[0] = __uint_as_float(d << 16); e3[1] = __uint_as_float(d & 0xffff0000u);
    acc[0] += wv * e0;
    acc[1] += wv * e1;
    acc[2] += wv * e2;
    acc[3] += wv * e3;
}
// scalar variant for epilogue self-loop add
__device__ __forceinline__ void acc8(float* acc, float4 u, float w) {
    unsigned a = __float_as_uint(u.x), b = __float_as_uint(u.y);
    unsigned c = __float_as_uint(u.z), d = __float_as_uint(u.w);
    acc[0] += w * __uint_as_float(a << 16);
    acc[1] += w * __uint_as_float(a & 0xffff0000u);
    acc[2] += w * __uint_as_float(b << 16);
    acc[3] += w * __uint_as_float(b & 0xffff0000u);
    acc[4] += w * __uint_as_float(c << 16);
    acc[5] += w * __uint_as_float(c & 0xffff0000u);
    acc[6] += w * __uint_as_float(d << 16);
    acc[7] += w * __uint_as_float(d & 0xffff0000u);
}
// packed edge meta: low 16 = src row, high 16 = ew * 2^16 (truncated). CACHED load.
__device__ __forceinline__ void edge_meta(const unsigned* p, int& r, float& w) {
    unsigned v = *p;
    r = (int)(v & 0xffffu);
    w = (float)(v >> 16) * (1.0f / 65536.0f);
}

// ---------------- init: fill/sums = 0 ----------------
__global__ void k_init(int* fill, float* sums) {
    int i = blockIdx.x * 256 + threadIdx.x;
    if (i < NN) fill[i] = 0;
    if (i < 2 * NF) sums[i] = 0.0f;
}

__global__ void k_zero_stats(float* sums) {
    int i = threadIdx.x;
    if (i < 2 * NF) sums[i] = 0.0f;
}

// ---------------- convert W (f32, o-major k-contig) -> bf16 ----------------
__global__ void k_cvtw(const float4* __restrict__ W, ushort4* __restrict__ Wh) {
    int idx = blockIdx.x * 256 + threadIdx.x;
    if (idx >= NF * NF / 4) return;
    float4 v = W[idx];
    ushort4 o;
    o.x = f2bf(v.x); o.y = f2bf(v.y); o.z = f2bf(v.z); o.w = f2bf(v.w);
    Wh[idx] = o;
}

// ------- scatter edges into fixed-capacity buckets: 1 atomic + one 4B nt store -----
// (round-0 form, measured best: nt store 77us; cached store 85us / 58MB writes)
__global__ void k_scatter(const int* __restrict__ ei, const float* __restrict__ ew,
                          int* fill, unsigned* __restrict__ bkt, int E) {
    int e = blockIdx.x * 256 + threadIdx.x;
    if (e >= E) return;
    int row = ei[e];
    int col = ei[E + e];
    unsigned q = (unsigned)(ew[e] * 65536.0f);        // trunc; ew<1 => q<=65535
    int pos = atomicAdd(&fill[col], 1);
    unsigned v = ((unsigned)row) | (q << 16);
    __builtin_nontemporal_store(v, &bkt[(size_t)col * CAP + pos]);
}

// ------- per-col degree from bucket (exact int sum of ewq), emit scales -----------
// s1 = dinv^2 (hops 1-2 row scale = D^-1), s2 = dinv (hop-3 scale & input pre-scale)
__global__ void k_deg(const unsigned* __restrict__ bkt, const int* __restrict__ fill,
                      float* __restrict__ s1, float* __restrict__ s2) {
    int i = blockIdx.x * 256 + threadIdx.x;
    if (i >= NN) return;
    int cnt = fill[i];
    unsigned sq = 0;
    const unsigned* p = bkt + (size_t)i * CAP;
    for (int e = 0; e < cnt; e++) sq += (p[e] >> 16);
    float deg = 1.0f + (float)sq * (1.0f / 65536.0f);
    float di = rsqrtf(deg);
    s2[i] = di;
    s1[i] = di * di;
}

// ---------------- concat (cell ++ sub), pre-scale by dinv, f32 -> bf16 ------------
__global__ void k_concat_h(const float4* __restrict__ cell, const float4* __restrict__ sub,
                           const float* __restrict__ dinv, ushort4* __restrict__ xh) {
    int idx = blockIdx.x * 256 + threadIdx.x;          // float4 index
    if (idx >= NN * (NF / 4)) return;
    const int CELL4 = NCELL * (NF / 4);
    float4 v = (idx < CELL4) ? cell[idx] : sub[idx - CELL4];
    float di = dinv[idx >> 6];
    ushort4 o;
    o.x = f2bf(v.x * di); o.y = f2bf(v.y * di);
    o.z = f2bf(v.z * di); o.w = f2bf(v.w * di);
    xh[idx] = o;
}

// ------------- one hop: t = (A+I) x, then row-scale; bf16 in/out, f32 accum --------
// 1 wave per node; 32 lanes span the 512B row (16B/lane); halves process even/odd
// edges. SOFTWARE-PIPELINED metas: batch i+1's 8 metas load while batch i's rows
// are accumulated -> the meta->rowaddr serial chain leaves the critical path.
// Self-row + scale issued at wave start. f32x2 accum -> v_pk_fma_f32.
__global__ __launch_bounds__(256) void k_prop(const ushort* __restrict__ xin,
                                              ushort* __restrict__ xout,
                                              const int* __restrict__ fill,
                                              const unsigned* __restrict__ bkt,
                                              const float* __restrict__ scale) {
    int n = blockIdx.x * 4 + (threadIdx.x >> 6);
    int lane = threadIdx.x & 63;
    int half = lane >> 5;              // 0: even edges, 1: odd edges
    int fb = lane & 31;                // features fb*8 .. fb*8+7
    const float4* xrow = (const float4*)xin;    // row r = x4[r*32 + fb]
    const unsigned* base = bkt + (size_t)n * CAP;
    int cnt = fill[n];
    float4 uself = xrow[n * 32 + fb];  // early: self-loop row (same lines both halves)
    float sc = scale[n];               // early: row scale
    f32x2 acc[4];
    #pragma unroll
    for (int i = 0; i < 4; i++) { acc[i][0] = 0.f; acc[i][1] = 0.f; }
    int steps = cnt >> 1;
    int it = 0;
    int e = half;
    if (8 <= steps) {
        unsigned m[8];
        #pragma unroll
        for (int j = 0; j < 8; j++) m[j] = base[e + 2 * j];
        for (;;) {
            int   r[8];
            float w[8];
            #pragma unroll
            for (int j = 0; j < 8; j++) {
                r[j] = (int)(m[j] & 0xffffu);
                w[j] = (float)(m[j] >> 16) * (1.0f / 65536.0f);
            }
            float4 u[8];
            #pragma unroll
            for (int j = 0; j < 8; j++) u[j] = xrow[r[j] * 32 + fb];
            it += 8; e += 16;
            bool more = (it + 8 <= steps);
            if (more) {
                #pragma unroll
                for (int j = 0; j < 8; j++) m[j] = base[e + 2 * j];  // prefetch next batch
            }
            #pragma unroll
            for (int j = 0; j < 8; j++) acc8v(acc, u[j], w[j]);
            if (!more) break;
        }
    }
    for (; it + 4 <= steps; it += 4, e += 8) {
        int r0, r1, r2, r3; float w0, w1, w2, w3;
        edge_meta(base + e,     r0, w0);
        edge_meta(base + e + 2, r1, w1);
        edge_meta(base + e + 4, r2, w2);
        edge_meta(base + e + 6, r3, w3);
        float4 u0 = xrow[r0 * 32 + fb];
        float4 u1 = xrow[r1 * 32 + fb];
        float4 u2 = xrow[r2 * 32 + fb];
        float4 u3 = xrow[r3 * 32 + fb];
        acc8v(acc, u0, w0); acc8v(acc, u1, w1); acc8v(acc, u2, w2); acc8v(acc, u3, w3);
    }
    for (; it < steps; ++it, e += 2) {
        int r0; float w0;
        edge_meta(base + e, r0, w0);
        float4 u0 = xrow[r0 * 32 + fb];
        acc8v(acc, u0, w0);
    }
    if ((cnt & 1) && half == 0) {          // odd remainder edge
        int r0; float w0;
        edge_meta(base + cnt - 1, r0, w0);
        float4 u0 = xrow[r0 * 32 + fb];
        acc8v(acc, u0, w0);
    }
    float accs[8];
    #pragma unroll
    for (int i = 0; i < 4; i++) { accs[2 * i] = acc[i][0]; accs[2 * i + 1] = acc[i][1]; }
    #pragma unroll
    for (int i = 0; i < 8; i++) accs[i] += __shfl_xor(accs[i], 32);
    if (half == 0) {
        acc8(accs, uself, 1.0f);           // self loop, raw weight 1
        #pragma unroll
        for (int i = 0; i < 8; i++) accs[i] *= sc;
        unsigned p0 = ((unsigned)f2bf(accs[1]) << 16) | f2bf(accs[0]);
        unsigned p1 = ((unsigned)f2bf(accs[3]) << 16) | f2bf(accs[2]);
        unsigned p2 = ((unsigned)f2bf(accs[5]) << 16) | f2bf(accs[4]);
        unsigned p3 = ((unsigned)f2bf(accs[7]) << 16) | f2bf(accs[6]);
        float4 o;
        o.x = __uint_as_float(p0); o.y = __uint_as_float(p1);
        o.z = __uint_as_float(p2); o.w = __uint_as_float(p3);
        ((float4*)xout)[n * 32 + fb] = o;
    }
}

// ------- y[m][o] = PReLU(bias[o] + sum_k A[m][k] W[o][k]) -> f32, + BN stats ------
// r9-verified: wave = 16 rows x full 256 cols (acc[16]); stats via LDS block-reduce
// (4 waves) -> 512 atomics/block. Invalid pad wave guarded (no early return).
__global__ __launch_bounds__(256) void k_gemm_fused(const short* __restrict__ A,  // NN x 256 bf16
                                                    const short* __restrict__ B,  // 256 x 256 bf16 (W)
                                                    const float* __restrict__ bias,
                                                    const float* __restrict__ pw,
                                                    float* __restrict__ y,        // NN x 256 f32
                                                    float* __restrict__ sums) {
    constexpr int RT = NN / 16;        // 1875 row tiles
    int w    = threadIdx.x >> 6;       // wave in block
    int lane = threadIdx.x & 63;
    int rt   = blockIdx.x * 4 + w;     // 4 row tiles per block
    int ml   = lane & 15;              // row in tile (A) / col in 16-tile (B, D)
    int q    = lane >> 4;              // quad: A/B k = q*8+j, D row = q*4+r
    bool valid = rt < RT;
    __shared__ float red[2][4][NF];    // [s|s2][wave][col] = 8 KB
    f32x4 acc[16];
    #pragma unroll
    for (int i = 0; i < 16; i++) acc[i] = (f32x4){0.f, 0.f, 0.f, 0.f};
    if (valid) {
        const short* arow = A + (rt * 16 + ml) * NF + q * 8;
        #pragma unroll
        for (int ks = 0; ks < 8; ks++) {
            bf16x8 a = *(const bf16x8*)(arow + ks * 32);
            #pragma unroll
            for (int nt = 0; nt < 16; nt++) {
                bf16x8 b = *(const bf16x8*)(B + (nt * 16 + ml) * NF + ks * 32 + q * 8);
                acc[nt] = __builtin_amdgcn_mfma_f32_16x16x32_bf16(a, b, acc[nt], 0, 0, 0);
            }
        }
    }
    #pragma unroll
    for (int nt = 0; nt < 16; nt++) {
        int col = nt * 16 + ml;
        float s = 0.f, s2 = 0.f;
        if (valid) {
            float bb = bias[col];
            float pc = pw[col];
            #pragma unroll
            for (int r = 0; r < 4; r++) {
                float v = acc[nt][r] + bb;
                v = (v >= 0.f) ? v : pc * v;
                s += v; s2 += v * v;
                y[(rt * 16 + q * 4 + r) * NF + col] = v;
            }
        }
        s  += __shfl_xor(s, 16);  s  += __shfl_xor(s, 32);
        s2 += __shfl_xor(s2, 16); s2 += __shfl_xor(s2, 32);
        if (lane < 16) { red[0][w][col] = s; red[1][w][col] = s2; }
    }
    __syncthreads();
    int t = threadIdx.x;               // t = col, all 256 threads
    float v0 = red[0][0][t] + red[0][1][t] + red[0][2][t] + red[0][3][t];
    float v1 = red[1][0][t] + red[1][1][t] + red[1][2][t] + red[1][3][t];
    atomicAdd(&sums[t], v0);
    atomicAdd(&sums[NF + t], v1);
}

// ---------------- finalize BN scale/shift ----------------
__global__ void k_finalize(const float* __restrict__ sums, const float* __restrict__ gamma,
                           const float* __restrict__ beta, float* __restrict__ ss) {
    int t = threadIdx.x;
    float mean = sums[t] / (float)NN;
    float var = sums[NF + t] / (float)NN - mean * mean;
    if (var < 0.f) var = 0.f;
    float istd = rsqrtf(var + EPS);
    float sc = gamma[t] * istd;
    ss[t] = sc;
    ss[NF + t] = beta[t] - mean * sc;
}

// -------- apply BN + dinv pre-scale: f32 y -> bf16 x (feeds next hop chain) -------
__global__ void k_apply_h(const float4* __restrict__ y, const float* __restrict__ ss,
                          const float* __restrict__ dinv, ushort4* __restrict__ xh) {
    int idx = blockIdx.x * 256 + threadIdx.x;          // float4 index
    if (idx >= NN * (NF / 4)) return;
    int f = (idx & 63) * 4;
    float di = dinv[idx >> 6];
    float4 v = y[idx];
    ushort4 o;
    o.x = f2bf((v.x * ss[f]     + ss[NF + f])     * di);
    o.y = f2bf((v.y * ss[f + 1] + ss[NF + f + 1]) * di);
    o.z = f2bf((v.z * ss[f + 2] + ss[NF + f + 2]) * di);
    o.w = f2bf((v.w * ss[f + 3] + ss[NF + f + 3]) * di);
    xh[idx] = o;
}

// ---------------- apply BN: f32 y -> f32 output ----------------
__global__ void k_apply_out(const float4* __restrict__ y, const float* __restrict__ ss,
                            float4* __restrict__ out) {
    int idx = blockIdx.x * 256 + threadIdx.x;          // float4 index
    if (idx >= NN * (NF / 4)) return;
    int f = (idx & 63) * 4;
    float4 v = y[idx];
    float4 o;
    o.x = v.x * ss[f]     + ss[NF + f];
    o.y = v.y * ss[f + 1] + ss[NF + f + 1];
    o.z = v.z * ss[f + 2] + ss[NF + f + 2];
    o.w = v.w * ss[f + 3] + ss[NF + f + 3];
    out[idx] = o;
}

extern "C" void kernel_launch(void* const* d_in, const int* in_sizes, int n_in,
                              void* d_out, int out_size, void* d_ws, size_t ws_size,
                              hipStream_t stream) {
    const float* cell  = (const float*)d_in[0];
    const float* sub   = (const float*)d_in[1];
    const int*   ei    = (const int*)  d_in[2];
    const float* ew    = (const float*)d_in[3];
    const float* W1    = (const float*)d_in[4];
    const float* bias1 = (const float*)d_in[5];
    const float* W2    = (const float*)d_in[6];
    const float* bias2 = (const float*)d_in[7];
    const float* pw    = (const float*)d_in[8];
    const float* gamma = (const float*)d_in[9];
    const float* beta  = (const float*)d_in[10];
    float* out = (float*)d_out;        // reference output dtype is float32
    const int E = in_sizes[3];         // 960000 directed edges

    char* ws = (char*)d_ws;
    size_t off = 0;
    auto alloc = [&](size_t bytes) -> void* {
        void* p = ws + off;
        off = (off + bytes + 255) & ~((size_t)255);
        return p;
    };
    ushort*   xh0  = (ushort*)  alloc((size_t)NN * NF * 2);     // bf16 x ping
    ushort*   xh1  = (ushort*)  alloc((size_t)NN * NF * 2);     // bf16 x pong
    float*    yf   = (float*)   alloc((size_t)NN * NF * 4);     // f32 prelu'd gemm out
    ushort*   W1h  = (ushort*)  alloc((size_t)NF * NF * 2);
    ushort*   W2h  = (ushort*)  alloc((size_t)NF * NF * 2);
    unsigned* bkt  = (unsigned*)alloc((size_t)NN * CAP * 4);    // 9.6 MB edge buckets
    int*      fill = (int*)     alloc((size_t)NN * 4);
    float*    s1   = (float*)   alloc((size_t)NN * 4);          // dinv^2
    float*    s2   = (float*)   alloc((size_t)NN * 4);          // dinv
    float*    sums = (float*)   alloc((size_t)2 * NF * 4);
    float*    ss   = (float*)   alloc((size_t)2 * NF * 4);

    const int gN  = (NN + 255) / 256;             // 118
    const int gE  = (E + 255) / 256;
    const int gV4 = (NN * NF / 4 + 255) / 256;    // 7500
    const int gW4 = (NF * NF / 4 + 255) / 256;    // 64
    const int gP  = NN / 4;                       // 7500 blocks, 1 wave/node
    const int gG  = (NN / 16 + 3) / 4;            // 469 blocks x 4 waves

    k_init<<<gN, 256, 0, stream>>>(fill, sums);
    k_cvtw<<<gW4, 256, 0, stream>>>((const float4*)W1, (ushort4*)W1h);
    k_cvtw<<<gW4, 256, 0, stream>>>((const float4*)W2, (ushort4*)W2h);
    k_scatter<<<gE, 256, 0, stream>>>(ei, ew, fill, bkt, E);
    k_deg<<<gN, 256, 0, stream>>>(bkt, fill, s1, s2);
    k_concat_h<<<gV4, 256, 0, stream>>>((const float4*)cell, (const float4*)sub, s2, (ushort4*)xh0);

    // ---------------- layer 1 ----------------
    k_prop<<<gP, 256, 0, stream>>>(xh0, xh1, fill, bkt, s1);
    k_prop<<<gP, 256, 0, stream>>>(xh1, xh0, fill, bkt, s1);
    k_prop<<<gP, 256, 0, stream>>>(xh0, xh1, fill, bkt, s2);
    k_gemm_fused<<<gG, 256, 0, stream>>>((const short*)xh1, (const short*)W1h, bias1, pw, yf, sums);
    k_finalize<<<1, 256, 0, stream>>>(sums, gamma, beta, ss);
    k_apply_h<<<gV4, 256, 0, stream>>>((const float4*)yf, ss, s2, (ushort4*)xh0);
    k_zero_stats<<<1, 512, 0, stream>>>(sums);

    // ---------------- layer 2 ----------------
    k_prop<<<gP, 256, 0, stream>>>(xh0, xh1, fill, bkt, s1);
    k_prop<<<gP, 256, 0, stream>>>(xh1, xh0, fill, bkt, s1);
    k_prop<<<gP, 256, 0, stream>>>(xh0, xh1, fill, bkt, s2);
    k_gemm_fused<<<gG, 256, 0, stream>>>((const short*)xh1, (const short*)W2h, bias2, pw, yf, sums);
    k_finalize<<<1, 256, 0, stream>>>(sums, gamma, beta, ss);
    k_apply_out<<<gV4, 256, 0, stream>>>((const float4*)yf, ss, (float4*)out);
}